// Round 9
// baseline (458.260 us; speedup 1.0000x reference)
//
#include <hip/hip_runtime.h>
#include <cstdint>
#include <cstddef>

// ---------------------------------------------------------------------------
// CADGroupingGNN: 3x GCNConv(128->128) + MLP classifier, N=50000, E=800000.
// Round 9: fp32 everywhere (bf16/fp16 h REJECTED: near-zero-degree nodes give
// snorm~1e4+, h~1e9, classifier logits are cancellation-dominated -> any
// low-precision h flips saturated sigmoids; fp32 is mandatory).
// Agg rework: one 64-lane wave per node (float2/lane, no intra-wave trip
// divergence) + 16-deep gather pipeline (16 rows in flight per wave).
// ---------------------------------------------------------------------------

__global__ __launch_bounds__(256) void k_init(int* __restrict__ cnt, int n) {
  int i = blockIdx.x * 256 + threadIdx.x;
  if (i < n) cnt[i] = 0;
}

// in-degree histogram; returned old count = edge's slot within its bucket
__global__ __launch_bounds__(256) void k_hist(
    const int* __restrict__ col, int* __restrict__ cnt,
    int* __restrict__ rank, int E) {
  int e = blockIdx.x * 256 + threadIdx.x;
  if (e < E) rank[e] = atomicAdd(&cnt[col[e]], 1);
}

// ---- exclusive scan of cnt[] over N elements (3 kernels) ----
__global__ __launch_bounds__(256) void k_scan1(
    const int* __restrict__ cnt, int* __restrict__ start,
    int* __restrict__ bsum, int n) {
  __shared__ int s[256];
  int t = threadIdx.x, idx = blockIdx.x * 256 + t;
  s[t] = (idx < n) ? cnt[idx] : 0;
  for (int d = 1; d < 256; d <<= 1) {
    __syncthreads();
    int x = (t >= d) ? s[t - d] : 0;
    __syncthreads();
    s[t] += x;
  }
  __syncthreads();
  if (idx < n) start[idx + 1] = s[t];          // inclusive, per-block
  if (t == 255) bsum[blockIdx.x] = s[255];
}

__global__ __launch_bounds__(256) void k_scan2(int* __restrict__ bsum, int nb) {
  __shared__ int s[256];
  int t = threadIdx.x;
  s[t] = (t < nb) ? bsum[t] : 0;
  for (int d = 1; d < 256; d <<= 1) {
    __syncthreads();
    int x = (t >= d) ? s[t - d] : 0;
    __syncthreads();
    s[t] += x;
  }
  __syncthreads();
  if (t < nb) bsum[t] = s[t];                  // inclusive block sums
}

__global__ __launch_bounds__(256) void k_scan3(
    int* __restrict__ start, const int* __restrict__ bsum, int n) {
  int b = blockIdx.x, idx = b * 256 + threadIdx.x;
  if (idx < n) {
    int off = (b > 0) ? bsum[b - 1] : 0;
    start[idx + 1] += off;
    if (idx == 0) start[0] = 0;
  }
}

// atomic-free bucket fill: p = start[col] + rank
__global__ __launch_bounds__(256) void k_fill(
    const int* __restrict__ attr, const float* __restrict__ emb,
    const int* __restrict__ row, const int* __restrict__ col,
    const int* __restrict__ rank, const int* __restrict__ start,
    int* __restrict__ srcs, float* __restrict__ ew_s, int E) {
  int e = blockIdx.x * 256 + threadIdx.x;
  if (e < E) {
    int p = start[col[e]] + rank[e];
    srcs[p] = row[e];
    ew_s[p] = emb[attr[e]];
  }
}

// per-node deterministic degree sum -> dinv, snorm
__global__ __launch_bounds__(256) void k_deg_csr(
    const int* __restrict__ start, const float* __restrict__ ew_s,
    float* __restrict__ dinv, float* __restrict__ snorm, int n) {
  int i = blockIdx.x * 256 + threadIdx.x;
  if (i >= n) return;
  int s = start[i], e = start[i + 1];
  float d = 1.0f;                              // self-loop weight
  for (int p = s; p < e; ++p) d += ew_s[p];
  float v = d > 0.f ? rsqrtf(d) : 0.f;
  dinv[i] = v;
  snorm[i] = v * v;
}

// per-node in-place weight normalization: ew_s[p] *= dinv[src]*dinv[i]
__global__ __launch_bounds__(256) void k_wts_csr(
    const int* __restrict__ start, const int* __restrict__ srcs,
    const float* __restrict__ dinv, float* __restrict__ ew_s, int n) {
  int i = blockIdx.x * 256 + threadIdx.x;
  if (i >= n) return;
  int s = start[i], e = start[i + 1];
  float di = dinv[i];
  for (int p = s; p < e; ++p) ew_s[p] = dinv[srcs[p]] * ew_s[p] * di;
}

__device__ __forceinline__ void agg_fma2(float s, const float2& v, float2& acc) {
  acc.x = fmaf(s, v.x, acc.x);
  acc.y = fmaf(s, v.y, acc.y);
}

// out[i][:] = bias + snorm[i]*h[i][:] + sum_e wts[e]*h[srcs[e]][:]
// ONE 64-lane wave per node; lane covers channels {2*lane, 2*lane+1} (float2).
// Full 512B row per gather instruction; 16-deep gather pipeline.
__global__ __launch_bounds__(256) void k_agg_csr(
    const float* __restrict__ h, const int* __restrict__ start,
    const int* __restrict__ srcs, const float* __restrict__ wts,
    const float* __restrict__ snorm, const float* __restrict__ bias,
    float* __restrict__ out, int n) {
  int i = (blockIdx.x * 256 + threadIdx.x) >> 6;   // node = global wave id
  if (i >= n) return;
  int lane = threadIdx.x & 63;
  const float2* h2 = (const float2*)h;             // row stride = 64 float2
  float2 acc = ((const float2*)bias)[lane];
  float sn = snorm[i];
  float2 hv = h2[(size_t)i * 64 + lane];
  acc.x = fmaf(sn, hv.x, acc.x);
  acc.y = fmaf(sn, hv.y, acc.y);

  int e = start[i], eend = start[i + 1];

  // head: advance to 4-edge alignment so int4/float4 loads are 16B-aligned
  while (e < eend && (e & 3)) {
    float w = wts[e];
    float2 v = h2[(size_t)srcs[e] * 64 + lane];
    agg_fma2(w, v, acc);
    ++e;
  }

  // 16-deep body: 4 broadcast index/weight vec-loads, 16 row-gathers in flight
  for (; e + 16 <= eend; e += 16) {
    int4   s0 = *(const int4*)&srcs[e];
    int4   s1 = *(const int4*)&srcs[e + 4];
    int4   s2 = *(const int4*)&srcs[e + 8];
    int4   s3 = *(const int4*)&srcs[e + 12];
    float4 w0 = *(const float4*)&wts[e];
    float4 w1 = *(const float4*)&wts[e + 4];
    float4 w2 = *(const float4*)&wts[e + 8];
    float4 w3 = *(const float4*)&wts[e + 12];
    float2 v0  = h2[(size_t)s0.x * 64 + lane];
    float2 v1  = h2[(size_t)s0.y * 64 + lane];
    float2 v2  = h2[(size_t)s0.z * 64 + lane];
    float2 v3  = h2[(size_t)s0.w * 64 + lane];
    float2 v4  = h2[(size_t)s1.x * 64 + lane];
    float2 v5  = h2[(size_t)s1.y * 64 + lane];
    float2 v6  = h2[(size_t)s1.z * 64 + lane];
    float2 v7  = h2[(size_t)s1.w * 64 + lane];
    float2 v8  = h2[(size_t)s2.x * 64 + lane];
    float2 v9  = h2[(size_t)s2.y * 64 + lane];
    float2 v10 = h2[(size_t)s2.z * 64 + lane];
    float2 v11 = h2[(size_t)s2.w * 64 + lane];
    float2 v12 = h2[(size_t)s3.x * 64 + lane];
    float2 v13 = h2[(size_t)s3.y * 64 + lane];
    float2 v14 = h2[(size_t)s3.z * 64 + lane];
    float2 v15 = h2[(size_t)s3.w * 64 + lane];
    agg_fma2(w0.x, v0, acc);  agg_fma2(w0.y, v1, acc);
    agg_fma2(w0.z, v2, acc);  agg_fma2(w0.w, v3, acc);
    agg_fma2(w1.x, v4, acc);  agg_fma2(w1.y, v5, acc);
    agg_fma2(w1.z, v6, acc);  agg_fma2(w1.w, v7, acc);
    agg_fma2(w2.x, v8, acc);  agg_fma2(w2.y, v9, acc);
    agg_fma2(w2.z, v10, acc); agg_fma2(w2.w, v11, acc);
    agg_fma2(w3.x, v12, acc); agg_fma2(w3.y, v13, acc);
    agg_fma2(w3.z, v14, acc); agg_fma2(w3.w, v15, acc);
  }

  // 8-edge step
  if (e + 8 <= eend) {
    int4   s0 = *(const int4*)&srcs[e];
    int4   s1 = *(const int4*)&srcs[e + 4];
    float4 w0 = *(const float4*)&wts[e];
    float4 w1 = *(const float4*)&wts[e + 4];
    float2 v0 = h2[(size_t)s0.x * 64 + lane];
    float2 v1 = h2[(size_t)s0.y * 64 + lane];
    float2 v2 = h2[(size_t)s0.z * 64 + lane];
    float2 v3 = h2[(size_t)s0.w * 64 + lane];
    float2 v4 = h2[(size_t)s1.x * 64 + lane];
    float2 v5 = h2[(size_t)s1.y * 64 + lane];
    float2 v6 = h2[(size_t)s1.z * 64 + lane];
    float2 v7 = h2[(size_t)s1.w * 64 + lane];
    agg_fma2(w0.x, v0, acc); agg_fma2(w0.y, v1, acc);
    agg_fma2(w0.z, v2, acc); agg_fma2(w0.w, v3, acc);
    agg_fma2(w1.x, v4, acc); agg_fma2(w1.y, v5, acc);
    agg_fma2(w1.z, v6, acc); agg_fma2(w1.w, v7, acc);
    e += 8;
  }

  // 4-edge step
  if (e + 4 <= eend) {
    int4   s0 = *(const int4*)&srcs[e];
    float4 w0 = *(const float4*)&wts[e];
    float2 v0 = h2[(size_t)s0.x * 64 + lane];
    float2 v1 = h2[(size_t)s0.y * 64 + lane];
    float2 v2 = h2[(size_t)s0.z * 64 + lane];
    float2 v3 = h2[(size_t)s0.w * 64 + lane];
    agg_fma2(w0.x, v0, acc); agg_fma2(w0.y, v1, acc);
    agg_fma2(w0.z, v2, acc); agg_fma2(w0.w, v3, acc);
    e += 4;
  }

  // tail
  for (; e < eend; ++e) {
    float w = wts[e];
    float2 v = h2[(size_t)srcs[e] * 64 + lane];
    agg_fma2(w, v, acc);
  }

  ((float2*)out)[(size_t)i * 64 + lane] = acc;
}

// GEMM: out[M x HOUT] = act( f(A[M x 128]) @ W[128 x HOUT] + bias )
// BN=64 col tiles; persistent blocks (W staged once); 2 blocks/CU.
// ACT: 0 none, 1 relu, 2 sigmoid. RELU_IN: relu applied to A on load.
template <int HOUT, int ACT, bool RELU_IN>
__global__ __launch_bounds__(256, 2) void k_gemm(
    const float* __restrict__ A, const float* __restrict__ W,
    const float* __restrict__ bias, float* __restrict__ out, int M) {
  constexpr int NCT = HOUT / 64;   // column tiles
  constexpr int W4R = HOUT / 4;    // float4 per W row
  __shared__ float Ws[128 * 64];   // 32 KB: this block's 64-col slice of W
  __shared__ float Xs[64][132];    // 33 KB

  const int t = threadIdx.x;
  const int ct = blockIdx.x % NCT;
  const int rt0 = blockIdx.x / NCT;
  const int rstride = gridDim.x / NCT;
  const int ntiles = (M + 63) >> 6;

  // stage Ws: 2048 float4
  for (int i = t; i < 128 * 16; i += 256) {
    int k = i >> 4, j4 = i & 15;
    ((float4*)Ws)[i] = ((const float4*)W)[k * W4R + ct * 16 + j4];
  }

  const int tc = t & 15;           // 16 column groups (4 cols each)
  const int tr = t >> 4;           // 16 row groups (4 rows each)
  const float4* A4 = (const float4*)A;

  for (int rt = rt0; rt < ntiles; rt += rstride) {
    __syncthreads();               // prev compute done (and Ws staged, 1st iter)
    const int m0 = rt << 6;
    for (int i = t; i < 64 * 32; i += 256) {
      int r = i >> 5, c4 = i & 31;
      int gr = m0 + r;
      float4 v = make_float4(0.f, 0.f, 0.f, 0.f);
      if (gr < M) v = A4[(size_t)gr * 32 + c4];
      if (RELU_IN) {
        v.x = fmaxf(v.x, 0.f); v.y = fmaxf(v.y, 0.f);
        v.z = fmaxf(v.z, 0.f); v.w = fmaxf(v.w, 0.f);
      }
      *(float4*)&Xs[r][c4 * 4] = v;
    }
    __syncthreads();

    float acc[4][4];
#pragma unroll
    for (int rr = 0; rr < 4; ++rr)
      acc[rr][0] = acc[rr][1] = acc[rr][2] = acc[rr][3] = 0.f;

#pragma unroll 4
    for (int k4 = 0; k4 < 32; ++k4) {
      float4 wv[4], av[4];
#pragma unroll
      for (int kk = 0; kk < 4; ++kk)
        wv[kk] = ((const float4*)Ws)[(k4 * 4 + kk) * 16 + tc];
#pragma unroll
      for (int rr = 0; rr < 4; ++rr)
        av[rr] = *(const float4*)&Xs[tr * 4 + rr][k4 * 4];
#pragma unroll
      for (int rr = 0; rr < 4; ++rr) {
        acc[rr][0] = fmaf(av[rr].x, wv[0].x, acc[rr][0]);
        acc[rr][1] = fmaf(av[rr].x, wv[0].y, acc[rr][1]);
        acc[rr][2] = fmaf(av[rr].x, wv[0].z, acc[rr][2]);
        acc[rr][3] = fmaf(av[rr].x, wv[0].w, acc[rr][3]);
        acc[rr][0] = fmaf(av[rr].y, wv[1].x, acc[rr][0]);
        acc[rr][1] = fmaf(av[rr].y, wv[1].y, acc[rr][1]);
        acc[rr][2] = fmaf(av[rr].y, wv[1].z, acc[rr][2]);
        acc[rr][3] = fmaf(av[rr].y, wv[1].w, acc[rr][3]);
        acc[rr][0] = fmaf(av[rr].z, wv[2].x, acc[rr][0]);
        acc[rr][1] = fmaf(av[rr].z, wv[2].y, acc[rr][1]);
        acc[rr][2] = fmaf(av[rr].z, wv[2].z, acc[rr][2]);
        acc[rr][3] = fmaf(av[rr].z, wv[2].w, acc[rr][3]);
        acc[rr][0] = fmaf(av[rr].w, wv[3].x, acc[rr][0]);
        acc[rr][1] = fmaf(av[rr].w, wv[3].y, acc[rr][1]);
        acc[rr][2] = fmaf(av[rr].w, wv[3].z, acc[rr][2]);
        acc[rr][3] = fmaf(av[rr].w, wv[3].w, acc[rr][3]);
      }
    }

#pragma unroll
    for (int rr = 0; rr < 4; ++rr) {
      int gr = m0 + tr * 4 + rr;
      if (gr >= M) continue;
      float4 v = make_float4(acc[rr][0], acc[rr][1], acc[rr][2], acc[rr][3]);
      if (bias) {
        const float4 bv = *(const float4*)&bias[ct * 64 + tc * 4];
        v.x += bv.x; v.y += bv.y; v.z += bv.z; v.w += bv.w;
      }
      if (ACT == 1) {
        v.x = fmaxf(v.x, 0.f); v.y = fmaxf(v.y, 0.f);
        v.z = fmaxf(v.z, 0.f); v.w = fmaxf(v.w, 0.f);
      } else if (ACT == 2) {
        v.x = 1.f / (1.f + __expf(-v.x));
        v.y = 1.f / (1.f + __expf(-v.y));
        v.z = 1.f / (1.f + __expf(-v.z));
        v.w = 1.f / (1.f + __expf(-v.w));
      }
      ((float4*)out)[(size_t)gr * W4R + ct * 16 + tc] = v;
    }
  }
}

extern "C" void kernel_launch(void* const* d_in, const int* in_sizes, int n_in,
                              void* d_out, int out_size, void* d_ws, size_t ws_size,
                              hipStream_t stream) {
  const float* x        = (const float*)d_in[0];
  const float* edge_emb = (const float*)d_in[1];
  const float* W1 = (const float*)d_in[2];  const float* b1 = (const float*)d_in[3];
  const float* W2 = (const float*)d_in[4];  const float* b2 = (const float*)d_in[5];
  const float* W3 = (const float*)d_in[6];  const float* b3 = (const float*)d_in[7];
  const float* cW1 = (const float*)d_in[8]; const float* cb1 = (const float*)d_in[9];
  const float* cW2 = (const float*)d_in[10]; const float* cb2 = (const float*)d_in[11];
  const int* eidx  = (const int*)d_in[12];
  const int* eattr = (const int*)d_in[13];

  const int N = in_sizes[0] / 128;
  const int E = in_sizes[13];
  const int* row = eidx;        // edge_index[0] = source
  const int* col = eidx + E;    // edge_index[1] = target

  float* out = (float*)d_out;

  // workspace layout, 16B-aligned slots (element counts rounded to x4)
  size_t off = 0;
  auto alloc4 = [&](size_t n) { size_t o = off; off += (n + 3) & ~(size_t)3; return o; };
  float* wsf = (float*)d_ws;
  int*   wsi = (int*)d_ws;

  float* dinv   = wsf + alloc4(N);
  float* snorm  = wsf + alloc4(N);
  int*   cnt    = wsi + alloc4(N);
  int*   start  = wsi + alloc4(N + 1);
  int*   bsum   = wsi + alloc4(256);
  int*   rank   = wsi + alloc4(E);
  int*   srcs   = wsi + alloc4(E);
  float* wts    = wsf + alloc4(E);   // raw ew, normalized in place
  float* bufA   = wsf + alloc4((size_t)N * 128);
  float* bufB   = wsf + alloc4((size_t)N * 128);

  const int gN  = (N + 255) / 256;
  const int gE  = (E + 255) / 256;
  const int gA  = (N * 64 + 255) / 256;   // one 64-lane wave per node
  const int nb  = gN;  // scan blocks
  const int gGemm = 512;   // persistent: 2 blocks/CU

  // ---- graph preprocessing (once, reused by all 3 layers) ----
  k_init<<<gN, 256, 0, stream>>>(cnt, N);
  k_hist<<<gE, 256, 0, stream>>>(col, cnt, rank, E);
  k_scan1<<<nb, 256, 0, stream>>>(cnt, start, bsum, N);
  k_scan2<<<1, 256, 0, stream>>>(bsum, nb);
  k_scan3<<<nb, 256, 0, stream>>>(start, bsum, N);
  k_fill<<<gE, 256, 0, stream>>>(eattr, edge_emb, row, col, rank, start,
                                 srcs, wts, E);
  k_deg_csr<<<gN, 256, 0, stream>>>(start, wts, dinv, snorm, N);
  k_wts_csr<<<gN, 256, 0, stream>>>(start, srcs, dinv, wts, N);

  // ---- layer 1 ----
  k_gemm<128, 0, false><<<gGemm, 256, 0, stream>>>(x, W1, nullptr, bufA, N);
  k_agg_csr<<<gA, 256, 0, stream>>>(bufA, start, srcs, wts, snorm, b1, bufB, N);
  // ---- layer 2 (relu fused into GEMM input load) ----
  k_gemm<128, 0, true><<<gGemm, 256, 0, stream>>>(bufB, W2, nullptr, bufA, N);
  k_agg_csr<<<gA, 256, 0, stream>>>(bufA, start, srcs, wts, snorm, b2, bufB, N);
  // ---- layer 3 ----
  k_gemm<128, 0, true><<<gGemm, 256, 0, stream>>>(bufB, W3, nullptr, bufA, N);
  k_agg_csr<<<gA, 256, 0, stream>>>(bufA, start, srcs, wts, snorm, b3, bufB, N);

  // ---- classifier ----
  k_gemm<128, 1, true><<<gGemm, 256, 0, stream>>>(bufB, cW1, cb1, bufA, N);
  k_gemm<64, 2, false><<<gGemm, 256, 0, stream>>>(bufA, cW2, cb2, out, N);
}